// Round 17
// baseline (17113.687 us; speedup 1.0000x reference)
//
#include <hip/hip_runtime.h>

typedef unsigned short u16;
typedef unsigned long long u64;
typedef __attribute__((ext_vector_type(8))) short short8;
typedef __attribute__((ext_vector_type(4))) float f32x4;

union U16x8 { uint4 u; short8 s; u16 h[8]; };

__device__ __forceinline__ float b2f(u16 u) {
  union { unsigned int i; float f; } x; x.i = ((unsigned int)u) << 16; return x.f;
}
__device__ __forceinline__ u16 f2b(float f) {
  union { float f; unsigned int i; } x; x.f = f;
  unsigned int r = x.i + 0x7FFFu + ((x.i >> 16) & 1u);
  return (u16)(r >> 16);
}
__device__ __forceinline__ float sig_(float x) { return 1.0f / (1.0f + __expf(-x)); }
__device__ __forceinline__ float tanh_(float x) {
  float e = __expf(2.0f * x);
  return 1.0f - 2.0f / (e + 1.0f);
}

#define BS_ 16640L  // 65*256, per-batch stride of buf_s

// ---------- convert reused weights fp32 -> bf16 into ws ----------
__global__ __launch_bounds__(256) void kprep(
    const float* __restrict__ a0, const float* __restrict__ a1,
    const float* __restrict__ a2, const float* __restrict__ a3,
    const float* __restrict__ a4, const float* __restrict__ a5,
    u16* __restrict__ dst)
{
  int i = blockIdx.x * 256 + threadIdx.x;
  const float* s; int o;
  if (i < 65536)        { s = a0; o = i; }
  else if (i < 851968)  { s = a1; o = i - 65536; }
  else if (i < 1114112) { s = a2; o = i - 851968; }
  else if (i < 1441792) { s = a3; o = i - 1114112; }
  else if (i < 1769472) { s = a4; o = i - 1441792; }
  else                  { s = a5; o = i - 1769472; }
  dst[i] = f2b(s[o]);
}

// ---------- phase 1 (MFMA): buf = selu(embed[tok] @ W_in^T + b), outputs0 head ----------
__global__ __launch_bounds__(256) void kbuf2(
    const int* __restrict__ tokens, const float* __restrict__ embed,
    const u16* __restrict__ w_inB, const float* __restrict__ b_in,
    const float* __restrict__ w_out, const float* __restrict__ b_out,
    float* __restrict__ out0, u16* __restrict__ buf_s, u16* __restrict__ padv)
{
  __shared__ u16 Wl[128 * 264];
  __shared__ u16 Bufl[64 * 264];
  const int tid = threadIdx.x;
  const int wv = tid >> 6, ln = tid & 63, l15 = ln & 15, lq = ln >> 4;

  int pos = blockIdx.x * 64 + wv * 16 + l15;
  int b = pos / 127, t = pos - b * 127;
  int tok = tokens[b * 127 + t];
  const float* arow = embed + (size_t)tok * 256 + lq * 8;
  short8 av[8];
#pragma unroll
  for (int kk = 0; kk < 8; ++kk) {
    float4 f0 = *(const float4*)(arow + kk * 32);
    float4 f1 = *(const float4*)(arow + kk * 32 + 4);
    U16x8 tmp;
    tmp.h[0] = f2b(f0.x); tmp.h[1] = f2b(f0.y); tmp.h[2] = f2b(f0.z); tmp.h[3] = f2b(f0.w);
    tmp.h[4] = f2b(f1.x); tmp.h[5] = f2b(f1.y); tmp.h[6] = f2b(f1.z); tmp.h[7] = f2b(f1.w);
    av[kk] = tmp.s;
  }

  const float SELU_A = 1.6732632423543772f, SELU_S = 1.0507009873554805f;
#pragma unroll 1
  for (int hf = 0; hf < 2; ++hf) {
    __syncthreads();
    {
      int col = tid >> 1, seg = tid & 1;
      const uint4* s = (const uint4*)(w_inB + (size_t)(hf * 128 + col) * 256 + seg * 128);
      uint4* d = (uint4*)(Wl + col * 264 + seg * 128);
#pragma unroll
      for (int i = 0; i < 16; ++i) d[i] = s[i];
    }
    __syncthreads();
#pragma unroll 1
    for (int t2 = 0; t2 < 8; ++t2) {
      f32x4 acc = {0.f, 0.f, 0.f, 0.f};
#pragma unroll
      for (int kk = 0; kk < 8; ++kk) {
        U16x8 bv; bv.u = *(const uint4*)(Wl + (t2 * 16 + l15) * 264 + kk * 32 + lq * 8);
        acc = __builtin_amdgcn_mfma_f32_16x16x32_bf16(av[kk], bv.s, acc, 0, 0, 0);
      }
      int col = hf * 128 + t2 * 16 + l15;
      float bi = b_in[col];
#pragma unroll
      for (int i = 0; i < 4; ++i) {
        float v = acc[i] + bi;
        v = (v > 0.0f) ? SELU_S * v : SELU_S * SELU_A * (__expf(v) - 1.0f);
        Bufl[(wv * 16 + lq * 4 + i) * 264 + col] = f2b(v);
      }
    }
  }
  __syncthreads();

  {
    int row = tid >> 2, seg = tid & 3;
    int pos2 = blockIdx.x * 64 + row;
    int b2 = pos2 / 127, t2p = pos2 - b2 * 127;
    u16* dst = 0;
    if (t2p <= 64) dst = buf_s + (size_t)b2 * BS_ + t2p * 256 + seg * 64;
    else if (t2p == 126 && b2 == 0) dst = padv + seg * 64;
    if (dst) {
      const uint4* s = (const uint4*)(Bufl + row * 264 + seg * 64);
      uint4* d = (uint4*)dst;
#pragma unroll
      for (int i = 0; i < 8; ++i) d[i] = s[i];
    }
  }
#pragma unroll 1
  for (int pp = 0; pp < 16; ++pp) {
    int p = wv * 16 + pp;
    uint2 hu = *(const uint2*)(Bufl + p * 264 + ln * 4);
    const u16* hh = (const u16*)&hu;
    float lg[3];
#pragma unroll
    for (int o = 0; o < 3; ++o) {
      float4 wvv = *(const float4*)(w_out + o * 256 + ln * 4);
      lg[o] = b2f(hh[0]) * wvv.x + b2f(hh[1]) * wvv.y + b2f(hh[2]) * wvv.z + b2f(hh[3]) * wvv.w;
    }
#pragma unroll
    for (int o = 0; o < 3; ++o)
      for (int off = 32; off > 0; off >>= 1) lg[o] += __shfl_down(lg[o], off);
    if (ln == 0) {
      float l0 = lg[0] + b_out[0];
      float l1 = lg[1] + b_out[1];
      float l2 = lg[2] + b_out[2];
      float m = fmaxf(l0, fmaxf(l1, l2));
      float lse = m + __logf(__expf(l0 - m) + __expf(l1 - m) + __expf(l2 - m));
      int pos3 = blockIdx.x * 64 + p;
      int b3 = pos3 / 127, t3 = pos3 - b3 * 127;
      size_t o0 = ((size_t)t3 * 1024 + b3) * 3;
      out0[o0 + 0] = l0 - lse;
      out0[o0 + 1] = l1 - lse;
      out0[o0 + 2] = l2 - lse;
    }
  }
}

struct SeqArgs {
  const u16* buf_s; const u16* padv;
  const u16* w_ihB; const u16* w_hhB;
  const u16* w_lB; const u16* w_rB; const u16* w_tB;
  const float* b_ih; const float* b_hh; const float* b_l;
  const float* w_out;
  float* lgp;
};

// ---------- persistent sequential phase, ROW-PARTITIONED ----------
// 64 blocks x 16 batch rows; each block computes ALL 256 hidden cols.
// th/tc/hR state is block-local (LDS bf16 h-state + f32 registers for cells)
// -> ZERO inter-block communication, no barriers, no coherent traffic.
// Weights stream from L2 (read-only, resident). Math: identical channel/kk
// MFMA order and identical fp32/bf16 round-trips as the verified baseline.
__global__ __launch_bounds__(256, 1) void kseq(SeqArgs A) {
  __shared__ u16 thL[2][16][264];   // th double buffer, rows x cols (padded)
  __shared__ u16 hRh[2][16][264];   // reduce-output h history (j&1)
  const int tid = threadIdx.x;
  const int wv = tid >> 6, ln = tid & 63, l15 = ln & 15, lq = ln >> 4;
  const long r0 = (long)blockIdx.x * 16;   // this block's first batch row

  for (int i = tid; i < 16 * 264; i += 256) ((u16*)thL[0])[i] = 0;

  // per-lane column bases: 4 col-tiles of 16, cols c = wv*64 + ct*16 + l15
  int cc[4];
#pragma unroll
  for (int ct = 0; ct < 4; ++ct) cc[ct] = wv * 64 + ct * 16 + l15;
  float bt[4][4], br[4][5], wo[4][3];
#pragma unroll
  for (int ct = 0; ct < 4; ++ct) {
#pragma unroll
    for (int q = 0; q < 4; ++q) bt[ct][q] = A.b_ih[q * 256 + cc[ct]] + A.b_hh[q * 256 + cc[ct]];
#pragma unroll
    for (int q = 0; q < 5; ++q) br[ct][q] = A.b_l[q * 256 + cc[ct]];
#pragma unroll
    for (int o = 0; o < 3; ++o) wo[ct][o] = A.w_out[o * 256 + cc[ct]];
  }
  float tcv[4][4], rcv[4][4];
#pragma unroll
  for (int ct = 0; ct < 4; ++ct)
#pragma unroll
    for (int i = 0; i < 4; ++i) { tcv[ct][i] = 0.f; rcv[ct][i] = 0.f; }
  __syncthreads();

  const u16* bufs = A.buf_s;
  const int arow = (int)(lq * 8);  // lane's k-offset within a 32-slice

#pragma unroll 1
  for (int t = 0; t < 127; ++t) {
    // ---- static schedule (verbatim semantics; hR channels -> LDS parity) ----
    int k; const u16 *gA1 = 0, *gA2 = 0; long S1 = 0, S2 = 0;
    int hpar = 0; bool c1 = false, c2 = false, isR = false;
    if (t == 0)      { k = 0;  gA1 = A.padv; S1 = 0;   gA2 = A.padv; S2 = 0; }
    else if (t == 1) { k = 1;  gA1 = bufs;           S1 = BS_; gA2 = A.padv; S2 = 0; }
    else if (t == 2) { k = 2;  gA1 = bufs + 256;     S1 = BS_; gA2 = bufs;       S2 = BS_; }
    else if (t == 3) { k = 3;  gA1 = bufs + 512;     S1 = BS_; gA2 = bufs + 256; S2 = BS_; isR = true; }
    else if (t == 126) { k = 64; c1 = true; hpar = 0; gA2 = bufs; S2 = BS_; isR = true; }
    else if ((t & 1) == 0) { int i = (t - 2) / 2; k = i + 2; c1 = true; hpar = i & 1; gA2 = bufs; S2 = BS_; }
    else { int i = (t - 3) / 2; k = i + 3; gA1 = bufs + (i + 2) * 256; S1 = BS_; c2 = true; hpar = i & 1; isR = true; }

    const u16* thin = &thL[t & 1][0][0];
    u16* thout = &thL[(t + 1) & 1][0][0];

    // ---- tracker MFMA: ch outer, kk inner (baseline order), 4 col-tiles x 4 gates ----
    f32x4 acc[4][4];
#pragma unroll
    for (int ct = 0; ct < 4; ++ct)
#pragma unroll
      for (int g = 0; g < 4; ++g) acc[ct][g] = (f32x4){0.f, 0.f, 0.f, 0.f};

#define TRK_CH(CH, AF_EXPR)                                                     \
  {                                                                             \
    _Pragma("unroll 1")                                                         \
    for (int kk = 0; kk < 8; ++kk) {                                            \
      U16x8 af; af.u = (AF_EXPR);                                               \
      _Pragma("unroll")                                                         \
      for (int ct = 0; ct < 4; ++ct) {                                          \
        _Pragma("unroll")                                                       \
        for (int g = 0; g < 4; ++g) {                                           \
          U16x8 bv;                                                             \
          if (CH < 3)                                                           \
            bv.u = *(const uint4*)(A.w_ihB + (size_t)(g * 256 + cc[ct]) * 768 + CH * 256 + kk * 32 + arow); \
          else                                                                  \
            bv.u = *(const uint4*)(A.w_hhB + (size_t)(g * 256 + cc[ct]) * 256 + kk * 32 + arow); \
          acc[ct][g] = __builtin_amdgcn_mfma_f32_16x16x32_bf16(af.s, bv.s, acc[ct][g], 0, 0, 0); \
        }                                                                       \
      }                                                                         \
    }                                                                           \
  }

    TRK_CH(0, (*(const uint4*)(bufs + k * 256 + (r0 + l15) * BS_ + kk * 32 + arow)))
    if (c1) { TRK_CH(1, (*(const uint4*)(&hRh[hpar][l15][kk * 32 + arow]))) }
    else    { TRK_CH(1, (*(const uint4*)(gA1 + (r0 + l15) * S1 + kk * 32 + arow))) }
    if (c2) { TRK_CH(2, (*(const uint4*)(&hRh[hpar][l15][kk * 32 + arow]))) }
    else    { TRK_CH(2, (*(const uint4*)(gA2 + (r0 + l15) * S2 + kk * 32 + arow))) }
    TRK_CH(3, (*(const uint4*)(thin + l15 * 264 + kk * 32 + arow)))
#undef TRK_CH

#pragma unroll
    for (int ct = 0; ct < 4; ++ct)
#pragma unroll
      for (int i = 0; i < 4; ++i) {
        float gi = acc[ct][0][i] + bt[ct][0];
        float gf = acc[ct][1][i] + bt[ct][1];
        float gg = acc[ct][2][i] + bt[ct][2];
        float go = acc[ct][3][i] + bt[ct][3];
        float tcn = sig_(gf) * tcv[ct][i] + sig_(gi) * tanh_(gg);
        tcv[ct][i] = tcn;
        thout[(lq * 4 + i) * 264 + cc[ct]] = f2b(sig_(go) * tanh_(tcn));
      }
    __syncthreads();

    if (isR) {
      int j; const u16 *gL = 0, *gR = 0; int lcase; const u16 *lCg = 0, *rCg = 0; int hR_par = 0;
      if (t == 3) { j = 1; gL = bufs + 256; gR = bufs + 512;
                    lcase = 0; lCg = bufs + 256; rCg = bufs + 512; }
      else if (t == 126) { j = 63; gL = bufs; lcase = 2; lCg = bufs; hR_par = 0; }
      else { int i2 = (t - 3) / 2; j = i2 + 1; lcase = 1; hR_par = i2 & 1;
             gR = bufs + (i2 + 2) * 256; rCg = bufs + (i2 + 2) * 256; }

      f32x4 acc2[4][5];
#pragma unroll
      for (int ct = 0; ct < 4; ++ct)
#pragma unroll
        for (int g = 0; g < 5; ++g) acc2[ct][g] = (f32x4){0.f, 0.f, 0.f, 0.f};

#define RED_CH(WB, AF_EXPR)                                                     \
  {                                                                             \
    _Pragma("unroll 1")                                                         \
    for (int kk = 0; kk < 8; ++kk) {                                            \
      U16x8 af; af.u = (AF_EXPR);                                               \
      _Pragma("unroll")                                                         \
      for (int ct = 0; ct < 4; ++ct) {                                          \
        _Pragma("unroll")                                                       \
        for (int g = 0; g < 5; ++g) {                                           \
          U16x8 bv;                                                             \
          bv.u = *(const uint4*)((WB) + (size_t)(g * 256 + cc[ct]) * 256 + kk * 32 + arow); \
          acc2[ct][g] = __builtin_amdgcn_mfma_f32_16x16x32_bf16(af.s, bv.s, acc2[ct][g], 0, 0, 0); \
        }                                                                       \
      }                                                                         \
    }                                                                           \
  }

      if (lcase == 1) { RED_CH(A.w_lB, (*(const uint4*)(&hRh[hR_par][l15][kk * 32 + arow]))) }
      else            { RED_CH(A.w_lB, (*(const uint4*)(gL + (r0 + l15) * BS_ + kk * 32 + arow))) }
      if (lcase == 2) { RED_CH(A.w_rB, (*(const uint4*)(&hRh[hR_par][l15][kk * 32 + arow]))) }
      else            { RED_CH(A.w_rB, (*(const uint4*)(gR + (r0 + l15) * BS_ + kk * 32 + arow))) }
      RED_CH(A.w_tB, (*(const uint4*)(thout + l15 * 264 + kk * 32 + arow)))
#undef RED_CH

#pragma unroll
      for (int ct = 0; ct < 4; ++ct) {
        float hv4[4];
#pragma unroll
        for (int i = 0; i < 4; ++i) {
          int row = lq * 4 + i;
          float a_ = acc2[ct][0][i] + br[ct][0];
          float ig = acc2[ct][1][i] + br[ct][1];
          float f1g = acc2[ct][2][i] + br[ct][2];
          float f2g = acc2[ct][3][i] + br[ct][3];
          float og = acc2[ct][4][i] + br[ct][4];
          float lc = (lcase == 1) ? rcv[ct][i] : b2f(lCg[(r0 + row) * BS_ + cc[ct]]);
          float rc = (lcase == 2) ? rcv[ct][i] : b2f(rCg[(r0 + row) * BS_ + cc[ct]]);
          float cn = tanh_(a_) * sig_(ig) + sig_(f1g) * lc + sig_(f2g) * rc;
          float hn = sig_(og) * tanh_(cn);
          rcv[ct][i] = cn;
          hRh[j & 1][row][cc[ct]] = f2b(hn);
          hv4[i] = hn;
        }
        // per-16-col-tile head-logit partials (baseline-identical grouping)
        float pr[12];
#pragma unroll
        for (int o = 0; o < 3; ++o)
#pragma unroll
          for (int i = 0; i < 4; ++i) pr[o * 4 + i] = hv4[i] * wo[ct][o];
#pragma unroll
        for (int u = 0; u < 12; ++u)
#pragma unroll
          for (int mm = 1; mm < 16; mm <<= 1) pr[u] += __shfl_xor(pr[u], mm);
        if (l15 == 0) {
          int ng = wv * 4 + ct;
          float* lgo = A.lgp + (size_t)((j - 1) * 16 + ng) * 3072;
#pragma unroll
          for (int o = 0; o < 3; ++o)
#pragma unroll
            for (int i = 0; i < 4; ++i)
              lgo[(size_t)(r0 + lq * 4 + i) * 3 + o] = pr[o * 4 + i];
        }
      }
      __syncthreads();
    }
  }
}

// ---------- finalize outs1: sum 16 per-tile partials, log-softmax ----------
__global__ __launch_bounds__(256) void kfin(const float* __restrict__ lgp,
    const float* __restrict__ b_out, float* __restrict__ out1)
{
  int r = blockIdx.x * 256 + threadIdx.x;
  if (r >= 64512) return;
  int j = r >> 10, row = r & 1023;
  float l0 = b_out[0], l1 = b_out[1], l2 = b_out[2];
#pragma unroll
  for (int nn = 0; nn < 16; ++nn) {
    const float* p = lgp + ((size_t)(j * 16 + nn) * 1024 + row) * 3;
    l0 += p[0]; l1 += p[1]; l2 += p[2];
  }
  float m = fmaxf(l0, fmaxf(l1, l2));
  float lse = m + __logf(__expf(l0 - m) + __expf(l1 - m) + __expf(l2 - m));
  out1[r * 3 + 0] = l0 - lse;
  out1[r * 3 + 1] = l1 - lse;
  out1[r * 3 + 2] = l2 - lse;
}

extern "C" void kernel_launch(void* const* d_in, const int* in_sizes, int n_in,
                              void* d_out, int out_size, void* d_ws, size_t ws_size,
                              hipStream_t stream) {
  const int* tokens   = (const int*)d_in[0];
  const float* embed  = (const float*)d_in[2];
  const float* w_in   = (const float*)d_in[3];
  const float* b_in   = (const float*)d_in[4];
  const float* left_w = (const float*)d_in[5];
  const float* left_b = (const float*)d_in[6];
  const float* right_w= (const float*)d_in[7];
  const float* track_w= (const float*)d_in[8];
  const float* w_ih   = (const float*)d_in[9];
  const float* w_hh   = (const float*)d_in[10];
  const float* b_ih   = (const float*)d_in[11];
  const float* b_hh   = (const float*)d_in[12];
  const float* w_out  = (const float*)d_in[13];
  const float* b_out  = (const float*)d_in[14];
  float* out = (float*)d_out;

  char* ws = (char*)d_ws;
  u16* wB    = (u16*)ws;                      // bf16 weight pool (4 MB)
  u16* w_inB = wB;
  u16* w_ihB = wB + 65536;
  u16* w_hhB = wB + 851968;
  u16* w_lB  = wB + 1114112;
  u16* w_rB  = wB + 1441792;
  u16* w_tB  = wB + 1769472;
  u16* buf_s = (u16*)(ws + 4194304);          // [1024][65][256] bf16
  u16* padv  = (u16*)(ws + 38273024);         // [256] bf16
  float* lgp = (float*)(ws + 40374784);       // [63][16][1024][3] f32 partials

  kprep<<<8192, 256, 0, stream>>>(w_in, w_ih, w_hh, left_w, right_w, track_w, wB);
  kbuf2<<<2032, 256, 0, stream>>>(tokens, embed, w_inB, b_in, w_out, b_out, out, buf_s, padv);

  SeqArgs sa;
  sa.buf_s = buf_s; sa.padv = padv;
  sa.w_ihB = w_ihB; sa.w_hhB = w_hhB;
  sa.w_lB = w_lB; sa.w_rB = w_rB; sa.w_tB = w_tB;
  sa.b_ih = b_ih; sa.b_hh = b_hh; sa.b_l = left_b;
  sa.w_out = w_out; sa.lgp = lgp;
  kseq<<<64, 256, 0, stream>>>(sa);

  kfin<<<252, 256, 0, stream>>>(lgp, b_out, out + 390144);
}